// Round 7
// baseline (256.311 us; speedup 1.0000x reference)
//
#include <hip/hip_runtime.h>

#define N_NODES 100000
#define N_EDGES 20000
#define N_INC   800000
#define D_IN    256
#define D_H     16
#define D_OUT   40

// two-pass LDS radix list builder; fine buckets:
// edge buckets: 32 edges, 625 buckets; cap 1600 recs (mean 1280, +8.9 sigma)
// node buckets: 256 nodes, 392 buckets; cap 2400 recs (mean 2048, +7.8 sigma)
#define EBS    32
#define NBE    625
#define ECAP   1600
#define VBS    256
#define NBV    392
#define VCAP   2400
// round-7: halved part tiles -> shorter per-block serial path, finer GEMM mix
#define TE     2048
#define EPART  391          // ceil(800000/2048)
#define TV     3072
#define NPART  261          // ceil(800000/3072)
#define PTOT   652          // EPART + NPART
#define GEMM_BLOCKS 782     // 6250 waves / 8 waves-per-512-block
// interleave: groups of 11 = 5 part + 6 gemm (652:782 ~ 5:6); 131 groups
#define GRID_K1 1441

typedef short bf16x8 __attribute__((ext_vector_type(8)));
typedef float f32x4  __attribute__((ext_vector_type(4)));

__device__ __forceinline__ unsigned short f2bf(float f) {
    unsigned u = __float_as_uint(f);
    unsigned r = u + 0x7FFF + ((u >> 16) & 1);   // round-to-nearest-even
    return (unsigned short)(r >> 16);
}

// block-wide exclusive scan over 512 threads: wave shfl-scan + 8-word combine.
__device__ __forceinline__ int block_exscan512(int local, int* sc8) {
    int t = threadIdx.x, lane = t & 63, wid = t >> 6;
    int s = local;
#pragma unroll
    for (int o = 1; o < 64; o <<= 1) {
        int x = __shfl_up(s, o, 64);
        if (lane >= o) s += x;
    }
    if (lane == 63) sc8[wid] = s;
    __syncthreads();
    int wbase = 0;
#pragma unroll
    for (int i = 0; i < 8; ++i) if (i < wid) wbase += sc8[i];
    return wbase + s - local;
}

// ---------------- K0: pack W1 into MFMA B-frag layout; zero bucket counters ----
__global__ __launch_bounds__(512) void init_kernel(
    const float* __restrict__ W1, unsigned short* __restrict__ bfrag,
    int* __restrict__ cnts /* cnt_be(625) @0 ++ cnt_bv(392) @640 */) {
    int t = threadIdx.x;
    for (int i = t; i < 1040; i += 512) cnts[i] = 0;
    int c = t >> 6, l = t & 63;          // 512 threads = 8 chunks x 64 lanes
    int n = l & 15, q = l >> 4;
    unsigned short v[8];
#pragma unroll
    for (int j = 0; j < 8; ++j)
        v[j] = f2bf(W1[(c * 32 + q * 8 + j) * D_H + n]);
    *(int4*)(bfrag + (size_t)(c * 64 + l) * 8) = *(int4*)v;
}

// ---------------- K1: interleaved part-edge | part-node | GEMM -----------------
// single-pass part: incidences read ONCE into registers; hist+scatter from regs.
// edge rec: v(17) | (e&31)<<17 | (e>>5)<<22   node rec: e(15) | (v&255)<<15 | (v>>8)<<23
union SMemP {
    struct { int lrec[TE]; int lhist[NBE]; int lbase[NBE];
             int gbase[NBE]; int lcur[NBE]; int sc[8]; } pe;
    struct { int lrec[TV]; int lhist[NBV]; int lbase[NBV];
             int gbase[NBV]; int lcur[NBV]; int sc[8]; } pn;
};

__global__ __launch_bounds__(512) void part_gemm_kernel(
    const int* __restrict__ ni, const int* __restrict__ ei,
    const float* __restrict__ w,
    int* __restrict__ cnt_be, int* __restrict__ cnt_bv,
    int* __restrict__ staged_e, int* __restrict__ staged_v,
    const float* __restrict__ H, const unsigned short* __restrict__ bfrag,
    float* __restrict__ T) {
    __shared__ SMemP sm;
    int t = threadIdx.x;
    int m11 = blockIdx.x % 11, g11 = blockIdx.x / 11;
    bool is_part = (m11 < 5);
    int pj = g11 * 5 + m11;              // part job id (if is_part)
    int gj = g11 * 6 + (m11 - 5);        // gemm job id (if !is_part)
    if (is_part && pj >= PTOT) return;
    if (!is_part && gj >= GEMM_BLOCKS) return;

    if (!is_part) {
        // ---- GEMM: T[v] = (H @ W1)[v] * w[v], one wave per 16x16 tile ----
        int wave = (gj * 512 + t) >> 6;
        if (wave >= N_NODES / 16) return;        // wave-uniform guard
        int lane = t & 63;
        int m = lane & 15, q = lane >> 4;
        int row0 = wave * 16;
        const float* hp = H + (size_t)(row0 + m) * D_IN + q * 8;
        bf16x8 bf[8];
        const int4* bp = (const int4*)bfrag;
#pragma unroll
        for (int c = 0; c < 8; ++c) {
            int4 raw = bp[c * 64 + lane];
            bf[c] = *(bf16x8*)&raw;
        }
        f32x4 acc = {0.f, 0.f, 0.f, 0.f};
#pragma unroll
        for (int c = 0; c < 8; ++c) {
            float4 lo = *(const float4*)(hp + c * 32);
            float4 hi = *(const float4*)(hp + c * 32 + 4);
            bf16x8 af;
            af[0] = f2bf(lo.x); af[1] = f2bf(lo.y); af[2] = f2bf(lo.z); af[3] = f2bf(lo.w);
            af[4] = f2bf(hi.x); af[5] = f2bf(hi.y); af[6] = f2bf(hi.z); af[7] = f2bf(hi.w);
            acc = __builtin_amdgcn_mfma_f32_16x16x32_bf16(af, bf[c], acc, 0, 0, 0);
        }
        // C/D layout: col = lane&15, row = q*4 + reg; pre-scale row by w
#pragma unroll
        for (int r = 0; r < 4; ++r) {
            int row = row0 + q * 4 + r;
            T[(size_t)row * D_H + m] = acc[r] * w[row];
        }
    } else if (pj < EPART) {
        int base = pj * TE;
        int rec[TE / 512];
        for (int i = t; i < NBE; i += 512) sm.pe.lhist[i] = 0;
        __syncthreads();
#pragma unroll
        for (int r = 0; r < TE / 512; ++r) {
            int idx = base + r * 512 + t;
            rec[r] = -1;
            if (idx < N_INC) {
                int e = ei[idx], v = ni[idx];
                int key = e >> 5;
                rec[r] = v | ((e & 31) << 17) | (key << 22);
                atomicAdd(&sm.pe.lhist[key], 1);
            }
        }
        __syncthreads();
        // 625 bins, 2 per thread
        int b0 = 2 * t, b1 = 2 * t + 1;
        int h0 = (b0 < NBE) ? sm.pe.lhist[b0] : 0;
        int h1 = (b1 < NBE) ? sm.pe.lhist[b1] : 0;
        int ex = block_exscan512(h0 + h1, sm.pe.sc);
        if (b0 < NBE) {
            sm.pe.lbase[b0] = ex; sm.pe.lcur[b0] = ex;
            sm.pe.gbase[b0] = h0 ? (b0 * ECAP + atomicAdd(&cnt_be[b0], h0)) : 0;
        }
        if (b1 < NBE) {
            int ex1 = ex + h0;
            sm.pe.lbase[b1] = ex1; sm.pe.lcur[b1] = ex1;
            sm.pe.gbase[b1] = h1 ? (b1 * ECAP + atomicAdd(&cnt_be[b1], h1)) : 0;
        }
        __syncthreads();
#pragma unroll
        for (int r = 0; r < TE / 512; ++r) {
            if (rec[r] != -1) {
                int key = ((unsigned)rec[r]) >> 22;
                int p = atomicAdd(&sm.pe.lcur[key], 1);
                sm.pe.lrec[p] = rec[r];
            }
        }
        __syncthreads();
        int total = min(TE, N_INC - base);
        for (int i = t; i < total; i += 512) {
            int rr = sm.pe.lrec[i];
            int bk = ((unsigned)rr) >> 22;
            int dst = sm.pe.gbase[bk] + (i - sm.pe.lbase[bk]);
            if (dst < (bk + 1) * ECAP) staged_e[dst] = rr;
        }
    } else {
        int base = (pj - EPART) * TV;
        int rec[TV / 512];
        for (int i = t; i < NBV; i += 512) sm.pn.lhist[i] = 0;
        __syncthreads();
#pragma unroll
        for (int r = 0; r < TV / 512; ++r) {
            int idx = base + r * 512 + t;
            rec[r] = -1;
            if (idx < N_INC) {
                int e = ei[idx], v = ni[idx];
                int key = v >> 8;
                rec[r] = e | ((v & 255) << 15) | (key << 23);
                atomicAdd(&sm.pn.lhist[key], 1);
            }
        }
        __syncthreads();
        int h = (t < NBV) ? sm.pn.lhist[t] : 0;
        int ex = block_exscan512(h, sm.pn.sc);
        if (t < NBV) {
            sm.pn.lbase[t] = ex; sm.pn.lcur[t] = ex;
            sm.pn.gbase[t] = h ? (t * VCAP + atomicAdd(&cnt_bv[t], h)) : 0;
        }
        __syncthreads();
#pragma unroll
        for (int r = 0; r < TV / 512; ++r) {
            if (rec[r] != -1) {
                int key = ((unsigned)rec[r]) >> 23;
                int p = atomicAdd(&sm.pn.lcur[key], 1);
                sm.pn.lrec[p] = rec[r];
            }
        }
        __syncthreads();
        int total = min(TV, N_INC - base);
        for (int i = t; i < total; i += 512) {
            int rr = sm.pn.lrec[i];
            int bk = ((unsigned)rr) >> 23;
            int dst = sm.pn.gbase[bk] + (i - sm.pn.lbase[bk]);
            if (dst < (bk + 1) * VCAP) staged_v[dst] = rr;
        }
    }
}

// ---------------- K2: edge sort + fused gatherA layer-1 (625) | node sort (392) -
union SMemS {
    struct { int lsort[ECAP]; int hist[EBS]; int cursor[EBS]; int lbeg[EBS]; } e;
    struct { int lsort[VCAP]; int hist[VBS]; int cursor[VBS]; int sc[8]; } v;
};

__global__ __launch_bounds__(512) void sortE_gA1_sortN_kernel(
    const int* __restrict__ cnt_be, int* __restrict__ staged_e,
    int2* __restrict__ off_e2,
    const int* __restrict__ cnt_bv, int* __restrict__ staged_v,
    int2* __restrict__ off_v2,
    const float* __restrict__ T, const float* __restrict__ w,
    float* __restrict__ e_den, float* __restrict__ e_feat) {
    __shared__ SMemS sm;
    int t = threadIdx.x;
    if (blockIdx.x < NBE) {
        int b = blockIdx.x;
        int beg = b * ECAP, cnt = min(cnt_be[b], ECAP);
        if (t < EBS) sm.e.hist[t] = 0;
        __syncthreads();
        int rec[4], key[4], nr = 0;
#pragma unroll
        for (int r = 0; r < 4; ++r) {
            int k = r * 512 + t;
            if (k < cnt) {
                rec[nr] = staged_e[beg + k];
                key[nr] = (rec[nr] >> 17) & 31;
                atomicAdd(&sm.e.hist[key[nr]], 1);
                ++nr;
            }
        }
        __syncthreads();
        if (t < EBS) {
            int hh = sm.e.hist[t], s = hh;
#pragma unroll
            for (int o = 1; o < EBS; o <<= 1) {
                int x = __shfl_up(s, o, 64);
                if (t >= o) s += x;
            }
            int ex = s - hh;
            sm.e.cursor[t] = ex; sm.e.lbeg[t] = ex;
            off_e2[b * EBS + t] = make_int2(beg + ex, beg + ex + hh);
        }
        __syncthreads();
        for (int r = 0; r < nr; ++r) {
            int p = atomicAdd(&sm.e.cursor[key[r]], 1);
            sm.e.lsort[p] = rec[r];
        }
        __syncthreads();
        // writeback sorted records for gatherA layer-2
        for (int i = t; i < cnt; i += 512) staged_e[beg + i] = sm.e.lsort[i];
        // fused gatherA layer-1: 32 edges x 16 lanes, records from LDS.
        // batch-of-8: 8 independent LDS index reads, then 8 independent T gathers.
        int el = t >> 4, j = t & 15;
        int lo = sm.e.lbeg[el], hi = lo + sm.e.hist[el];
        float acc = 0.f;
        int k = lo;
        while (k < hi) {
            int m = hi - k; if (m > 8) m = 8;
            int vv[8];
#pragma unroll
            for (int i = 0; i < 8; ++i) vv[i] = (i < m) ? (sm.e.lsort[k + i] & 0x1FFFF) : 0;
#pragma unroll
            for (int i = 0; i < 8; ++i)
                if (i < m) acc += T[(size_t)vv[i] * D_H + j];
            k += 8;
        }
        // denominator: lanes split the w-gather, xor-reduce within 16-cluster
        float den = 0.f;
        for (int k2 = lo + j; k2 < hi; k2 += 16) den += w[sm.e.lsort[k2] & 0x1FFFF];
#pragma unroll
        for (int o = 1; o < 16; o <<= 1) den += __shfl_xor(den, o, 64);
        int e = b * EBS + el;                    // 625*32 == 20000 exactly
        e_feat[(size_t)e * D_H + j] = acc / fmaxf(den, 1e-6f);
        if (j == 0) e_den[e] = den;
    } else {
        int b = blockIdx.x - NBE;
        int beg = b * VCAP, cnt = min(cnt_bv[b], VCAP);
        for (int i = t; i < VBS; i += 512) sm.v.hist[i] = 0;
        __syncthreads();
        int rec[5], key[5], nr = 0;
#pragma unroll
        for (int r = 0; r < 5; ++r) {
            int k = r * 512 + t;
            if (k < cnt) {
                rec[nr] = staged_v[beg + k];
                key[nr] = (rec[nr] >> 15) & 255;
                atomicAdd(&sm.v.hist[key[nr]], 1);
                ++nr;
            }
        }
        __syncthreads();
        int hh = (t < VBS) ? sm.v.hist[t] : 0;
        int ex = block_exscan512(hh, sm.v.sc);
        if (t < VBS) {
            sm.v.cursor[t] = ex;
            int n = b * VBS + t;
            if (n < N_NODES) off_v2[n] = make_int2(beg + ex, beg + ex + hh);
        }
        __syncthreads();
        for (int r = 0; r < nr; ++r) {
            int p = atomicAdd(&sm.v.cursor[key[r]], 1);
            sm.v.lsort[p] = rec[r];
        }
        __syncthreads();
        for (int i = t; i < cnt; i += 512) staged_v[beg + i] = sm.v.lsort[i];
    }
}

// ---------------- K3: gatherB layer 1: 4 lanes/node, relu(mean+b1)*w ------------
// batch-of-8 record prefetch: 8 independent index loads then 8 row gathers.
__global__ __launch_bounds__(512) void gatherB1_kernel(
    const int2* __restrict__ off_v2, const int* __restrict__ staged_v,
    const float* __restrict__ e_feat, const float* __restrict__ w,
    const float* __restrict__ b1, float* __restrict__ out) {
    int t = blockIdx.x * 512 + threadIdx.x;
    int n = t >> 2;
    if (n >= N_NODES) return;
    int c = (t & 3) << 2;
    int2 be = off_v2[n];
    f32x4 acc = {0.f, 0.f, 0.f, 0.f};
    int k = be.x;
    while (k < be.y) {
        int m = be.y - k; if (m > 8) m = 8;
        int recs[8];
#pragma unroll
        for (int i = 0; i < 8; ++i) recs[i] = (i < m) ? staged_v[k + i] : 0;
#pragma unroll
        for (int i = 0; i < 8; ++i)
            if (i < m) acc += *(const f32x4*)(e_feat + (size_t)(recs[i] & 0x7FFF) * D_H + c);
        k += 8;
    }
    float inv = 1.f / fmaxf((float)(be.y - be.x), 1.f);
    f32x4 bb = *(const f32x4*)(b1 + c);
    float wn = w[n];
    f32x4 r;
#pragma unroll
    for (int i = 0; i < 4; ++i) r[i] = fmaxf(acc[i] * inv + bb[i], 0.f) * wn;
    *(f32x4*)(out + (size_t)n * D_H + c) = r;
}

// ---------------- K4: gatherA layer-2 (reuses e_den, sorted staged_e) -----------
__global__ __launch_bounds__(512) void gatherA2_kernel(
    const int2* __restrict__ off_e2, const int* __restrict__ staged_e,
    const float* __restrict__ X, const float* __restrict__ e_den,
    float* __restrict__ e_feat) {
    int e = (blockIdx.x * 512 + threadIdx.x) >> 6;
    if (e >= N_EDGES) return;
    int lane = threadIdx.x & 63;
    int g = lane >> 2, c = (lane & 3) << 2;
    int2 be = off_e2[e];
    f32x4 acc = {0.f, 0.f, 0.f, 0.f};
    for (int k = be.x + g; k < be.y; k += 16) {
        int rec = staged_e[k];
        int v = rec & 0x1FFFF;
        acc += *(const f32x4*)(X + (size_t)v * D_H + c);
    }
#pragma unroll
    for (int s = 4; s <= 32; s <<= 1) {
        acc[0] += __shfl_xor(acc[0], s, 64);
        acc[1] += __shfl_xor(acc[1], s, 64);
        acc[2] += __shfl_xor(acc[2], s, 64);
        acc[3] += __shfl_xor(acc[3], s, 64);
    }
    if (lane < 4) {
        float inv = 1.f / fmaxf(e_den[e], 1e-6f);
        f32x4 r = acc * inv;
        *(f32x4*)(e_feat + (size_t)e * D_H + c) = r;
    }
}

// ---------------- K5: gatherB layer 2 + W2 matmul + log_softmax -----------------
__global__ __launch_bounds__(512) void gatherB2_final_kernel(
    const int2* __restrict__ off_v2, const int* __restrict__ staged_v,
    const float* __restrict__ e_feat,
    const float* __restrict__ W2, const float* __restrict__ b2,
    float* __restrict__ out) {
    __shared__ float sy[128 * 20];
    __shared__ float sW2[D_H * D_OUT];
    __shared__ float sb2[D_OUT];
    int t = threadIdx.x;
    for (int i = t; i < D_H * D_OUT; i += 512) sW2[i] = W2[i];
    if (t < D_OUT) sb2[t] = b2[t];
    int nl = t >> 2, c = (t & 3) << 2;
    int n = blockIdx.x * 128 + nl;
    f32x4 y = {0.f, 0.f, 0.f, 0.f};
    if (n < N_NODES) {
        int2 be = off_v2[n];
        f32x4 acc = {0.f, 0.f, 0.f, 0.f};
        int k = be.x;
        while (k < be.y) {
            int m = be.y - k; if (m > 8) m = 8;
            int recs[8];
#pragma unroll
            for (int i = 0; i < 8; ++i) recs[i] = (i < m) ? staged_v[k + i] : 0;
#pragma unroll
            for (int i = 0; i < 8; ++i)
                if (i < m) acc += *(const f32x4*)(e_feat + (size_t)(recs[i] & 0x7FFF) * D_H + c);
            k += 8;
        }
        float inv = 1.f / fmaxf((float)(be.y - be.x), 1.f);
        y = acc * inv;
    }
    *(f32x4*)(sy + nl * 20 + c) = y;
    __syncthreads();
    if (n >= N_NODES) return;
    int c0 = (t & 3) * 10;
    float z[10];
#pragma unroll
    for (int i = 0; i < 10; ++i) z[i] = sb2[c0 + i];
#pragma unroll
    for (int jj = 0; jj < D_H; ++jj) {
        float yy = sy[nl * 20 + jj];
#pragma unroll
        for (int i = 0; i < 10; ++i) z[i] += yy * sW2[jj * D_OUT + c0 + i];
    }
    float m = z[0];
#pragma unroll
    for (int i = 1; i < 10; ++i) m = fmaxf(m, z[i]);
    m = fmaxf(m, __shfl_xor(m, 1, 64));
    m = fmaxf(m, __shfl_xor(m, 2, 64));
    float se = 0.f;
#pragma unroll
    for (int i = 0; i < 10; ++i) se += __expf(z[i] - m);
    se += __shfl_xor(se, 1, 64);
    se += __shfl_xor(se, 2, 64);
    float lse = m + __logf(se);
    float* op = out + (size_t)n * D_OUT + c0;
#pragma unroll
    for (int i = 0; i < 10; ++i) op[i] = z[i] - lse;
}

extern "C" void kernel_launch(void* const* d_in, const int* in_sizes, int n_in,
                              void* d_out, int out_size, void* d_ws, size_t ws_size,
                              hipStream_t stream) {
    const float* H  = (const float*)d_in[0];
    const float* w  = (const float*)d_in[1];
    const int*   ni = (const int*)d_in[2];
    const int*   ei = (const int*)d_in[3];
    const float* W1 = (const float*)d_in[4];
    const float* b1 = (const float*)d_in[5];
    const float* W2 = (const float*)d_in[6];
    const float* b2 = (const float*)d_in[7];
    float* out = (float*)d_out;

    // workspace layout (4-byte words)
    int*            ws_i     = (int*)d_ws;
    int*            cnt_be   = ws_i + 0;                      // 625
    int*            cnt_bv   = ws_i + 640;                    // 392
    unsigned short* bfrag    = (unsigned short*)(ws_i + 1040);// 4096 ush = 2048 w
    int2*           off_e2   = (int2*)(ws_i + 3088);          // 20000 int2
    int2*           off_v2   = (int2*)(ws_i + 43088);         // 100000 int2
    int*            staged_e = ws_i + 243088;                 // 625*1600
    int*            staged_v = ws_i + 1243088;                // 392*2400
    float*          e_den    = (float*)(ws_i + 2183888);      // 20000
    float*          T        = (float*)(ws_i + 2203888);      // 1,600,000
    float*          e_feat   = (float*)(ws_i + 3803888);      // 320,000
    float*          x1       = (float*)(ws_i + 4123888);      // 1,600,000
    // total 5,723,888 words = 22.9 MB

    init_kernel<<<1, 512, 0, stream>>>(W1, bfrag, cnt_be);

    part_gemm_kernel<<<GRID_K1, 512, 0, stream>>>(
        ni, ei, w, cnt_be, cnt_bv, staged_e, staged_v, H, bfrag, T);

    // edge sort + fused layer-1 edge aggregation || node sort
    sortE_gA1_sortN_kernel<<<NBE + NBV, 512, 0, stream>>>(
        cnt_be, staged_e, off_e2, cnt_bv, staged_v, off_v2, T, w, e_den, e_feat);

    gatherB1_kernel<<<782, 512, 0, stream>>>(off_v2, staged_v, e_feat, w, b1, x1);

    gatherA2_kernel<<<2500, 512, 0, stream>>>(off_e2, staged_e, x1, e_den, e_feat);

    gatherB2_final_kernel<<<782, 512, 0, stream>>>(
        off_v2, staged_v, e_feat, W2, b2, out);
}

// Round 8
// 252.607 us; speedup vs baseline: 1.0147x; 1.0147x over previous
//
#include <hip/hip_runtime.h>

#define N_NODES 100000
#define N_EDGES 20000
#define N_INC   800000
#define D_IN    256
#define D_H     16
#define D_OUT   40

// two-pass LDS radix list builder; fine buckets (round-6 proven config):
// edge buckets: 32 edges, 625 buckets; cap 1600 recs (mean 1280, +8.9 sigma)
// node buckets: 256 nodes, 392 buckets; cap 2400 recs (mean 2048, +7.8 sigma)
#define EBS    32
#define NBE    625
#define ECAP   1600
#define VBS    256
#define NBV    392
#define VCAP   2400
#define TE     4096
#define EPART  196          // ceil(800000/4096)
#define TV     6144
#define NPART  131          // ceil(800000/6144)
#define PTOT   327
#define GEMM_BLOCKS 782     // 6250 waves / 8 waves-per-512-block
#define CPAD   16           // reservation counters: one per 64B line (L2 same-line atomics serialize)

typedef short bf16x8 __attribute__((ext_vector_type(8)));
typedef float f32x4  __attribute__((ext_vector_type(4)));

__device__ __forceinline__ unsigned short f2bf(float f) {
    unsigned u = __float_as_uint(f);
    unsigned r = u + 0x7FFF + ((u >> 16) & 1);   // round-to-nearest-even
    return (unsigned short)(r >> 16);
}

// block-wide exclusive scan over 512 threads: wave shfl-scan + 8-word combine.
__device__ __forceinline__ int block_exscan512(int local, int* sc8) {
    int t = threadIdx.x, lane = t & 63, wid = t >> 6;
    int s = local;
#pragma unroll
    for (int o = 1; o < 64; o <<= 1) {
        int x = __shfl_up(s, o, 64);
        if (lane >= o) s += x;
    }
    if (lane == 63) sc8[wid] = s;
    __syncthreads();
    int wbase = 0;
#pragma unroll
    for (int i = 0; i < 8; ++i) if (i < wid) wbase += sc8[i];
    return wbase + s - local;
}

// ---------------- K0: pack W1 into MFMA B-frag layout; zero bucket counters ----
__global__ __launch_bounds__(512) void init_kernel(
    const float* __restrict__ W1, unsigned short* __restrict__ bfrag,
    int* __restrict__ cnts /* (625+392)*CPAD ints */) {
    int t = threadIdx.x;
    for (int i = t; i < (NBE + NBV) * CPAD; i += 512) cnts[i] = 0;
    int c = t >> 6, l = t & 63;          // 512 threads = 8 chunks x 64 lanes
    int n = l & 15, q = l >> 4;
    unsigned short v[8];
#pragma unroll
    for (int j = 0; j < 8; ++j)
        v[j] = f2bf(W1[(c * 32 + q * 8 + j) * D_H + n]);
    *(int4*)(bfrag + (size_t)(c * 64 + l) * 8) = *(int4*)v;
}

// ---------------- K1a: partition (standalone, own counters) --------------------
// single-pass: incidences read ONCE into registers; hist+scatter from regs.
// edge rec: v(17) | (e&31)<<17 | (e>>5)<<22   node rec: e(15) | (v&255)<<15 | (v>>8)<<23
union SMemP {
    struct { int lrec[TE]; int lhist[NBE]; int lbase[NBE];
             int gbase[NBE]; int lcur[NBE]; int sc[8]; } pe;
    struct { int lrec[TV]; int lhist[NBV]; int lbase[NBV];
             int gbase[NBV]; int lcur[NBV]; int sc[8]; } pn;
};

__global__ __launch_bounds__(512) void part_kernel(
    const int* __restrict__ ni, const int* __restrict__ ei,
    int* __restrict__ cnt_be, int* __restrict__ cnt_bv,
    int* __restrict__ staged_e, int* __restrict__ staged_v) {
    __shared__ SMemP sm;
    int t = threadIdx.x;
    if (blockIdx.x < EPART) {
        int base = blockIdx.x * TE;
        int rec[TE / 512];
        for (int i = t; i < NBE; i += 512) sm.pe.lhist[i] = 0;
        __syncthreads();
#pragma unroll
        for (int r = 0; r < TE / 512; ++r) {
            int idx = base + r * 512 + t;
            rec[r] = -1;
            if (idx < N_INC) {
                int e = ei[idx], v = ni[idx];
                int key = e >> 5;
                rec[r] = v | ((e & 31) << 17) | (key << 22);
                atomicAdd(&sm.pe.lhist[key], 1);
            }
        }
        __syncthreads();
        // 625 bins, 2 per thread
        int b0 = 2 * t, b1 = 2 * t + 1;
        int h0 = (b0 < NBE) ? sm.pe.lhist[b0] : 0;
        int h1 = (b1 < NBE) ? sm.pe.lhist[b1] : 0;
        int ex = block_exscan512(h0 + h1, sm.pe.sc);
        if (b0 < NBE) {
            sm.pe.lbase[b0] = ex; sm.pe.lcur[b0] = ex;
            sm.pe.gbase[b0] = h0 ? (b0 * ECAP + atomicAdd(&cnt_be[b0 * CPAD], h0)) : 0;
        }
        if (b1 < NBE) {
            int ex1 = ex + h0;
            sm.pe.lbase[b1] = ex1; sm.pe.lcur[b1] = ex1;
            sm.pe.gbase[b1] = h1 ? (b1 * ECAP + atomicAdd(&cnt_be[b1 * CPAD], h1)) : 0;
        }
        __syncthreads();
#pragma unroll
        for (int r = 0; r < TE / 512; ++r) {
            if (rec[r] != -1) {
                int key = ((unsigned)rec[r]) >> 22;
                int p = atomicAdd(&sm.pe.lcur[key], 1);
                sm.pe.lrec[p] = rec[r];
            }
        }
        __syncthreads();
        int total = min(TE, N_INC - base);
        for (int i = t; i < total; i += 512) {
            int rr = sm.pe.lrec[i];
            int bk = ((unsigned)rr) >> 22;
            int dst = sm.pe.gbase[bk] + (i - sm.pe.lbase[bk]);
            if (dst < (bk + 1) * ECAP) staged_e[dst] = rr;
        }
    } else {
        int base = (blockIdx.x - EPART) * TV;
        int rec[TV / 512];
        for (int i = t; i < NBV; i += 512) sm.pn.lhist[i] = 0;
        __syncthreads();
#pragma unroll
        for (int r = 0; r < TV / 512; ++r) {
            int idx = base + r * 512 + t;
            rec[r] = -1;
            if (idx < N_INC) {
                int e = ei[idx], v = ni[idx];
                int key = v >> 8;
                rec[r] = e | ((v & 255) << 15) | (key << 23);
                atomicAdd(&sm.pn.lhist[key], 1);
            }
        }
        __syncthreads();
        int h = (t < NBV) ? sm.pn.lhist[t] : 0;
        int ex = block_exscan512(h, sm.pn.sc);
        if (t < NBV) {
            sm.pn.lbase[t] = ex; sm.pn.lcur[t] = ex;
            sm.pn.gbase[t] = h ? (t * VCAP + atomicAdd(&cnt_bv[t * CPAD], h)) : 0;
        }
        __syncthreads();
#pragma unroll
        for (int r = 0; r < TV / 512; ++r) {
            if (rec[r] != -1) {
                int key = ((unsigned)rec[r]) >> 23;
                int p = atomicAdd(&sm.pn.lcur[key], 1);
                sm.pn.lrec[p] = rec[r];
            }
        }
        __syncthreads();
        int total = min(TV, N_INC - base);
        for (int i = t; i < total; i += 512) {
            int rr = sm.pn.lrec[i];
            int bk = ((unsigned)rr) >> 23;
            int dst = sm.pn.gbase[bk] + (i - sm.pn.lbase[bk]);
            if (dst < (bk + 1) * VCAP) staged_v[dst] = rr;
        }
    }
}

// ---------------- K1b: GEMM standalone, deep-ILP -------------------------------
// T[v] = (H @ W1)[v] * w[v]; one wave per 16x16 tile. All 16 A-quads loaded
// up-front (16 outstanding loads; prior fused version was RA-squeezed to 32
// VGPRs and serialized the chunk loads -> latency-bound).
__global__ __launch_bounds__(512) void gemm_kernel(
    const float* __restrict__ H, const unsigned short* __restrict__ bfrag,
    const float* __restrict__ w, float* __restrict__ T) {
    int wave = (blockIdx.x * 512 + threadIdx.x) >> 6;
    if (wave >= N_NODES / 16) return;            // wave-uniform guard
    int lane = threadIdx.x & 63;
    int m = lane & 15, q = lane >> 4;
    int row0 = wave * 16;
    const float4* hp = (const float4*)(H + (size_t)(row0 + m) * D_IN) + q * 2;

    float4 la[16];
#pragma unroll
    for (int c = 0; c < 8; ++c) {
        la[2 * c]     = hp[c * 8];       // (c*32)/4
        la[2 * c + 1] = hp[c * 8 + 1];
    }
    bf16x8 bf[8];
    const int4* bp = (const int4*)bfrag;
#pragma unroll
    for (int c = 0; c < 8; ++c) {
        int4 raw = bp[c * 64 + lane];
        bf[c] = *(bf16x8*)&raw;
    }
    f32x4 acc = {0.f, 0.f, 0.f, 0.f};
#pragma unroll
    for (int c = 0; c < 8; ++c) {
        float4 lo = la[2 * c], hi = la[2 * c + 1];
        bf16x8 af;
        af[0] = f2bf(lo.x); af[1] = f2bf(lo.y); af[2] = f2bf(lo.z); af[3] = f2bf(lo.w);
        af[4] = f2bf(hi.x); af[5] = f2bf(hi.y); af[6] = f2bf(hi.z); af[7] = f2bf(hi.w);
        acc = __builtin_amdgcn_mfma_f32_16x16x32_bf16(af, bf[c], acc, 0, 0, 0);
    }
    // C/D layout: col = lane&15, row = q*4 + reg; pre-scale row by w
#pragma unroll
    for (int r = 0; r < 4; ++r) {
        int row = row0 + q * 4 + r;
        T[(size_t)row * D_H + m] = acc[r] * w[row];
    }
}

// ---------------- K2: edge sort + fused gatherA layer-1 (625) | node sort (392) -
union SMemS {
    struct { int lsort[ECAP]; int hist[EBS]; int cursor[EBS]; int lbeg[EBS]; } e;
    struct { int lsort[VCAP]; int hist[VBS]; int cursor[VBS]; int sc[8]; } v;
};

__global__ __launch_bounds__(512) void sortE_gA1_sortN_kernel(
    const int* __restrict__ cnt_be, int* __restrict__ staged_e,
    int2* __restrict__ off_e2,
    const int* __restrict__ cnt_bv, int* __restrict__ staged_v,
    int2* __restrict__ off_v2,
    const float* __restrict__ T, const float* __restrict__ w,
    float* __restrict__ e_den, float* __restrict__ e_feat) {
    __shared__ SMemS sm;
    int t = threadIdx.x;
    if (blockIdx.x < NBE) {
        int b = blockIdx.x;
        int beg = b * ECAP, cnt = min(cnt_be[b * CPAD], ECAP);
        if (t < EBS) sm.e.hist[t] = 0;
        __syncthreads();
        int rec[4], key[4], nr = 0;
#pragma unroll
        for (int r = 0; r < 4; ++r) {
            int k = r * 512 + t;
            if (k < cnt) {
                rec[nr] = staged_e[beg + k];
                key[nr] = (rec[nr] >> 17) & 31;
                atomicAdd(&sm.e.hist[key[nr]], 1);
                ++nr;
            }
        }
        __syncthreads();
        if (t < EBS) {
            int hh = sm.e.hist[t], s = hh;
#pragma unroll
            for (int o = 1; o < EBS; o <<= 1) {
                int x = __shfl_up(s, o, 64);
                if (t >= o) s += x;
            }
            int ex = s - hh;
            sm.e.cursor[t] = ex; sm.e.lbeg[t] = ex;
            off_e2[b * EBS + t] = make_int2(beg + ex, beg + ex + hh);
        }
        __syncthreads();
        for (int r = 0; r < nr; ++r) {
            int p = atomicAdd(&sm.e.cursor[key[r]], 1);
            sm.e.lsort[p] = rec[r];
        }
        __syncthreads();
        // writeback sorted records for gatherA layer-2
        for (int i = t; i < cnt; i += 512) staged_e[beg + i] = sm.e.lsort[i];
        // fused gatherA layer-1: 32 edges x 16 lanes, records from LDS
        int el = t >> 4, j = t & 15;
        int lo = sm.e.lbeg[el], hi = lo + sm.e.hist[el];
        float acc = 0.f;
        int k = lo;
        for (; k + 4 <= hi; k += 4) {           // 4-deep MLP
            int r0 = sm.e.lsort[k]     & 0x1FFFF;
            int r1 = sm.e.lsort[k + 1] & 0x1FFFF;
            int r2 = sm.e.lsort[k + 2] & 0x1FFFF;
            int r3 = sm.e.lsort[k + 3] & 0x1FFFF;
            float t0 = T[(size_t)r0 * D_H + j];
            float t1 = T[(size_t)r1 * D_H + j];
            float t2 = T[(size_t)r2 * D_H + j];
            float t3 = T[(size_t)r3 * D_H + j];
            acc += t0; acc += t1; acc += t2; acc += t3;
        }
        for (; k < hi; ++k) acc += T[(size_t)(sm.e.lsort[k] & 0x1FFFF) * D_H + j];
        // denominator: lanes split the w-gather, xor-reduce within 16-cluster
        float den = 0.f;
        for (int k2 = lo + j; k2 < hi; k2 += 16) den += w[sm.e.lsort[k2] & 0x1FFFF];
#pragma unroll
        for (int o = 1; o < 16; o <<= 1) den += __shfl_xor(den, o, 64);
        int e = b * EBS + el;                    // 625*32 == 20000 exactly
        e_feat[(size_t)e * D_H + j] = acc / fmaxf(den, 1e-6f);
        if (j == 0) e_den[e] = den;
    } else {
        int b = blockIdx.x - NBE;
        int beg = b * VCAP, cnt = min(cnt_bv[b * CPAD], VCAP);
        for (int i = t; i < VBS; i += 512) sm.v.hist[i] = 0;
        __syncthreads();
        int rec[5], key[5], nr = 0;
#pragma unroll
        for (int r = 0; r < 5; ++r) {
            int k = r * 512 + t;
            if (k < cnt) {
                rec[nr] = staged_v[beg + k];
                key[nr] = (rec[nr] >> 15) & 255;
                atomicAdd(&sm.v.hist[key[nr]], 1);
                ++nr;
            }
        }
        __syncthreads();
        int hh = (t < VBS) ? sm.v.hist[t] : 0;
        int ex = block_exscan512(hh, sm.v.sc);
        if (t < VBS) {
            sm.v.cursor[t] = ex;
            int n = b * VBS + t;
            if (n < N_NODES) off_v2[n] = make_int2(beg + ex, beg + ex + hh);
        }
        __syncthreads();
        for (int r = 0; r < nr; ++r) {
            int p = atomicAdd(&sm.v.cursor[key[r]], 1);
            sm.v.lsort[p] = rec[r];
        }
        __syncthreads();
        for (int i = t; i < cnt; i += 512) staged_v[beg + i] = sm.v.lsort[i];
    }
}

// ---------------- K3: gatherB layer 1: 4 lanes/node, relu(mean+b1)*w ------------
__global__ __launch_bounds__(512) void gatherB1_kernel(
    const int2* __restrict__ off_v2, const int* __restrict__ staged_v,
    const float* __restrict__ e_feat, const float* __restrict__ w,
    const float* __restrict__ b1, float* __restrict__ out) {
    int t = blockIdx.x * 512 + threadIdx.x;
    int n = t >> 2;
    if (n >= N_NODES) return;
    int c = (t & 3) << 2;
    int2 be = off_v2[n];
    f32x4 acc = {0.f, 0.f, 0.f, 0.f};
    for (int k = be.x; k < be.y; ++k) {
        int e = staged_v[k] & 0x7FFF;
        acc += *(const f32x4*)(e_feat + (size_t)e * D_H + c);
    }
    float inv = 1.f / fmaxf((float)(be.y - be.x), 1.f);
    f32x4 bb = *(const f32x4*)(b1 + c);
    float wn = w[n];
    f32x4 r;
#pragma unroll
    for (int i = 0; i < 4; ++i) r[i] = fmaxf(acc[i] * inv + bb[i], 0.f) * wn;
    *(f32x4*)(out + (size_t)n * D_H + c) = r;
}

// ---------------- K4: gatherA layer-2 (reuses e_den, sorted staged_e) -----------
__global__ __launch_bounds__(512) void gatherA2_kernel(
    const int2* __restrict__ off_e2, const int* __restrict__ staged_e,
    const float* __restrict__ X, const float* __restrict__ e_den,
    float* __restrict__ e_feat) {
    int e = (blockIdx.x * 512 + threadIdx.x) >> 6;
    if (e >= N_EDGES) return;
    int lane = threadIdx.x & 63;
    int g = lane >> 2, c = (lane & 3) << 2;
    int2 be = off_e2[e];
    f32x4 acc = {0.f, 0.f, 0.f, 0.f};
    for (int k = be.x + g; k < be.y; k += 16) {
        int rec = staged_e[k];
        int v = rec & 0x1FFFF;
        acc += *(const f32x4*)(X + (size_t)v * D_H + c);
    }
#pragma unroll
    for (int s = 4; s <= 32; s <<= 1) {
        acc[0] += __shfl_xor(acc[0], s, 64);
        acc[1] += __shfl_xor(acc[1], s, 64);
        acc[2] += __shfl_xor(acc[2], s, 64);
        acc[3] += __shfl_xor(acc[3], s, 64);
    }
    if (lane < 4) {
        float inv = 1.f / fmaxf(e_den[e], 1e-6f);
        f32x4 r = acc * inv;
        *(f32x4*)(e_feat + (size_t)e * D_H + c) = r;
    }
}

// ---------------- K5: gatherB layer 2 + W2 matmul + log_softmax -----------------
__global__ __launch_bounds__(512) void gatherB2_final_kernel(
    const int2* __restrict__ off_v2, const int* __restrict__ staged_v,
    const float* __restrict__ e_feat,
    const float* __restrict__ W2, const float* __restrict__ b2,
    float* __restrict__ out) {
    __shared__ float sy[128 * 20];
    __shared__ float sW2[D_H * D_OUT];
    __shared__ float sb2[D_OUT];
    int t = threadIdx.x;
    for (int i = t; i < D_H * D_OUT; i += 512) sW2[i] = W2[i];
    if (t < D_OUT) sb2[t] = b2[t];
    int nl = t >> 2, c = (t & 3) << 2;
    int n = blockIdx.x * 128 + nl;
    f32x4 y = {0.f, 0.f, 0.f, 0.f};
    if (n < N_NODES) {
        int2 be = off_v2[n];
        f32x4 acc = {0.f, 0.f, 0.f, 0.f};
        for (int k = be.x; k < be.y; ++k) {
            int e = staged_v[k] & 0x7FFF;
            acc += *(const f32x4*)(e_feat + (size_t)e * D_H + c);
        }
        float inv = 1.f / fmaxf((float)(be.y - be.x), 1.f);
        y = acc * inv;
    }
    *(f32x4*)(sy + nl * 20 + c) = y;
    __syncthreads();
    if (n >= N_NODES) return;
    int c0 = (t & 3) * 10;
    float z[10];
#pragma unroll
    for (int i = 0; i < 10; ++i) z[i] = sb2[c0 + i];
#pragma unroll
    for (int jj = 0; jj < D_H; ++jj) {
        float yy = sy[nl * 20 + jj];
#pragma unroll
        for (int i = 0; i < 10; ++i) z[i] += yy * sW2[jj * D_OUT + c0 + i];
    }
    float m = z[0];
#pragma unroll
    for (int i = 1; i < 10; ++i) m = fmaxf(m, z[i]);
    m = fmaxf(m, __shfl_xor(m, 1, 64));
    m = fmaxf(m, __shfl_xor(m, 2, 64));
    float se = 0.f;
#pragma unroll
    for (int i = 0; i < 10; ++i) se += __expf(z[i] - m);
    se += __shfl_xor(se, 1, 64);
    se += __shfl_xor(se, 2, 64);
    float lse = m + __logf(se);
    float* op = out + (size_t)n * D_OUT + c0;
#pragma unroll
    for (int i = 0; i < 10; ++i) op[i] = z[i] - lse;
}

extern "C" void kernel_launch(void* const* d_in, const int* in_sizes, int n_in,
                              void* d_out, int out_size, void* d_ws, size_t ws_size,
                              hipStream_t stream) {
    const float* H  = (const float*)d_in[0];
    const float* w  = (const float*)d_in[1];
    const int*   ni = (const int*)d_in[2];
    const int*   ei = (const int*)d_in[3];
    const float* W1 = (const float*)d_in[4];
    const float* b1 = (const float*)d_in[5];
    const float* W2 = (const float*)d_in[6];
    const float* b2 = (const float*)d_in[7];
    float* out = (float*)d_out;

    // workspace layout (4-byte words)
    int*            ws_i     = (int*)d_ws;
    int*            cnt_be   = ws_i + 0;                      // 625*16 = 10000
    int*            cnt_bv   = ws_i + 10000;                  // 392*16 = 6272
    unsigned short* bfrag    = (unsigned short*)(ws_i + 16272); // 4096 ush = 2048 w
    int2*           off_e2   = (int2*)(ws_i + 18320);         // 20000 int2
    int2*           off_v2   = (int2*)(ws_i + 58320);         // 100000 int2
    int*            staged_e = ws_i + 258320;                 // 625*1600
    int*            staged_v = ws_i + 1258320;                // 392*2400
    float*          e_den    = (float*)(ws_i + 2199120);      // 20000
    float*          T        = (float*)(ws_i + 2219120);      // 1,600,000
    float*          e_feat   = (float*)(ws_i + 3819120);      // 320,000
    float*          x1       = (float*)(ws_i + 4139120);      // 1,600,000
    // total 5,739,120 words = 23.0 MB

    init_kernel<<<1, 512, 0, stream>>>(W1, bfrag, cnt_be);

    part_kernel<<<PTOT, 512, 0, stream>>>(ni, ei, cnt_be, cnt_bv,
                                          staged_e, staged_v);

    gemm_kernel<<<GEMM_BLOCKS, 512, 0, stream>>>(H, bfrag, w, T);

    // edge sort + fused layer-1 edge aggregation || node sort
    sortE_gA1_sortN_kernel<<<NBE + NBV, 512, 0, stream>>>(
        cnt_be, staged_e, off_e2, cnt_bv, staged_v, off_v2, T, w, e_den, e_feat);

    gatherB1_kernel<<<782, 512, 0, stream>>>(off_v2, staged_v, e_feat, w, b1, x1);

    gatherA2_kernel<<<2500, 512, 0, stream>>>(off_e2, staged_e, x1, e_den, e_feat);

    gatherB2_final_kernel<<<782, 512, 0, stream>>>(
        off_v2, staged_v, e_feat, W2, b2, out);
}

// Round 10
// 242.020 us; speedup vs baseline: 1.0590x; 1.0437x over previous
//
#include <hip/hip_runtime.h>

#define N_NODES 100000
#define N_EDGES 20000
#define N_INC   800000
#define D_IN    256
#define D_H     16
#define D_OUT   40

// two-pass LDS radix list builder; fine buckets (round-6 proven config):
// edge buckets: 32 edges, 625 buckets; cap 1600 recs (mean 1280, +8.9 sigma)
// node buckets: 256 nodes, 392 buckets; cap 2400 recs (mean 2048, +7.8 sigma)
#define EBS    32
#define NBE    625
#define ECAP   1600
#define VBS    256
#define NBV    392
#define VCAP   2400
#define TE     4096
#define EPART  196          // ceil(800000/4096)
#define TV     6144
#define NPART  131          // ceil(800000/6144)
#define PTOT   327
#define GEMM_BLOCKS 782     // 6250 waves / 8 waves-per-512-block
#define GRID_K1 1120        // groups of 10: 3 part + 7 gemm (round-6 interleave)
#define CPAD   16           // one reservation counter per 64B line

typedef short bf16x8 __attribute__((ext_vector_type(8)));
typedef float f32x4  __attribute__((ext_vector_type(4)));

__device__ __forceinline__ unsigned short f2bf(float f) {
    unsigned u = __float_as_uint(f);
    unsigned r = u + 0x7FFF + ((u >> 16) & 1);   // round-to-nearest-even
    return (unsigned short)(r >> 16);
}

// block-wide exclusive scan over 512 threads: wave shfl-scan + 8-word combine.
__device__ __forceinline__ int block_exscan512(int local, int* sc8) {
    int t = threadIdx.x, lane = t & 63, wid = t >> 6;
    int s = local;
#pragma unroll
    for (int o = 1; o < 64; o <<= 1) {
        int x = __shfl_up(s, o, 64);
        if (lane >= o) s += x;
    }
    if (lane == 63) sc8[wid] = s;
    __syncthreads();
    int wbase = 0;
#pragma unroll
    for (int i = 0; i < 8; ++i) if (i < wid) wbase += sc8[i];
    return wbase + s - local;
}

// ---------------- K0: pack W1 into MFMA B-frag layout; zero bucket counters ----
__global__ __launch_bounds__(512) void init_kernel(
    const float* __restrict__ W1, unsigned short* __restrict__ bfrag,
    int* __restrict__ cnts /* (625+392)*CPAD ints */) {
    int t = threadIdx.x;
    for (int i = t; i < (NBE + NBV) * CPAD; i += 512) cnts[i] = 0;
    int c = t >> 6, l = t & 63;          // 512 threads = 8 chunks x 64 lanes
    int n = l & 15, q = l >> 4;
    unsigned short v[8];
#pragma unroll
    for (int j = 0; j < 8; ++j)
        v[j] = f2bf(W1[(c * 32 + q * 8 + j) * D_H + n]);
    *(int4*)(bfrag + (size_t)(c * 64 + l) * 8) = *(int4*)v;
}

// ---------------- K1: interleaved part-edge | part-node | GEMM -----------------
// launch_bounds(512,2): allow up to ~256 VGPRs so the GEMM branch can hold all
// 16 A-quads in flight (round-6/7 builds were RA-squeezed to 32 VGPRs -> ~2
// outstanding loads -> 1.3 TB/s latency-bound; Little's law at ~450cy L3 hit).
// edge rec: v(17) | (e&31)<<17 | (e>>5)<<22   node rec: e(15) | (v&255)<<15 | (v>>8)<<23
union SMemP {
    struct { int lrec[TE]; int lhist[NBE]; int lbase[NBE];
             int gbase[NBE]; int lcur[NBE]; int sc[8]; } pe;
    struct { int lrec[TV]; int lhist[NBV]; int lbase[NBV];
             int gbase[NBV]; int lcur[NBV]; int sc[8]; } pn;
};

__global__ __launch_bounds__(512, 2) void part_gemm_kernel(
    const int* __restrict__ ni, const int* __restrict__ ei,
    const float* __restrict__ w,
    int* __restrict__ cnt_be, int* __restrict__ cnt_bv,
    int* __restrict__ staged_e, int* __restrict__ staged_v,
    const float* __restrict__ H, const unsigned short* __restrict__ bfrag,
    float* __restrict__ T) {
    __shared__ SMemP sm;
    int t = threadIdx.x;
    int m10 = blockIdx.x % 10, g10 = blockIdx.x / 10;
    bool is_part = (m10 < 3);
    int pj = g10 * 3 + m10;              // part job id (if is_part)
    int gj = g10 * 7 + (m10 - 3);        // gemm job id (if !is_part)
    if (is_part && pj >= PTOT) return;
    if (!is_part && gj >= GEMM_BLOCKS) return;

    if (!is_part) {
        // ---- GEMM: T[v] = (H @ W1)[v] * w[v], one wave per 16x16 tile ----
        int wave = (gj * 512 + t) >> 6;
        if (wave >= N_NODES / 16) return;        // wave-uniform guard
        int lane = t & 63;
        int m = lane & 15, q = lane >> 4;
        int row0 = wave * 16;
        const float4* hp = (const float4*)(H + (size_t)(row0 + m) * D_IN) + q * 2;
        float4 la[16];                           // 16 outstanding loads (MLP fix)
#pragma unroll
        for (int c = 0; c < 8; ++c) {
            la[2 * c]     = hp[c * 8];
            la[2 * c + 1] = hp[c * 8 + 1];
        }
        bf16x8 bf[8];
        const int4* bp = (const int4*)bfrag;
#pragma unroll
        for (int c = 0; c < 8; ++c) {
            int4 raw = bp[c * 64 + lane];
            bf[c] = *(bf16x8*)&raw;
        }
        f32x4 acc = {0.f, 0.f, 0.f, 0.f};
#pragma unroll
        for (int c = 0; c < 8; ++c) {
            float4 lo = la[2 * c], hi = la[2 * c + 1];
            bf16x8 af;
            af[0] = f2bf(lo.x); af[1] = f2bf(lo.y); af[2] = f2bf(lo.z); af[3] = f2bf(lo.w);
            af[4] = f2bf(hi.x); af[5] = f2bf(hi.y); af[6] = f2bf(hi.z); af[7] = f2bf(hi.w);
            acc = __builtin_amdgcn_mfma_f32_16x16x32_bf16(af, bf[c], acc, 0, 0, 0);
        }
        // C/D layout: col = lane&15, row = q*4 + reg; pre-scale row by w
#pragma unroll
        for (int r = 0; r < 4; ++r) {
            int row = row0 + q * 4 + r;
            T[(size_t)row * D_H + m] = acc[r] * w[row];
        }
    } else if (pj < EPART) {
        int base = pj * TE;
        int rec[TE / 512];
        for (int i = t; i < NBE; i += 512) sm.pe.lhist[i] = 0;
        __syncthreads();
#pragma unroll
        for (int r = 0; r < TE / 512; ++r) {
            int idx = base + r * 512 + t;
            rec[r] = -1;
            if (idx < N_INC) {
                int e = ei[idx], v = ni[idx];
                int key = e >> 5;
                rec[r] = v | ((e & 31) << 17) | (key << 22);
                atomicAdd(&sm.pe.lhist[key], 1);
            }
        }
        __syncthreads();
        // 625 bins, 2 per thread
        int b0 = 2 * t, b1 = 2 * t + 1;
        int h0 = (b0 < NBE) ? sm.pe.lhist[b0] : 0;
        int h1 = (b1 < NBE) ? sm.pe.lhist[b1] : 0;
        int ex = block_exscan512(h0 + h1, sm.pe.sc);
        if (b0 < NBE) {
            sm.pe.lbase[b0] = ex; sm.pe.lcur[b0] = ex;
            sm.pe.gbase[b0] = h0 ? (b0 * ECAP + atomicAdd(&cnt_be[b0 * CPAD], h0)) : 0;
        }
        if (b1 < NBE) {
            int ex1 = ex + h0;
            sm.pe.lbase[b1] = ex1; sm.pe.lcur[b1] = ex1;
            sm.pe.gbase[b1] = h1 ? (b1 * ECAP + atomicAdd(&cnt_be[b1 * CPAD], h1)) : 0;
        }
        __syncthreads();
#pragma unroll
        for (int r = 0; r < TE / 512; ++r) {
            if (rec[r] != -1) {
                int key = ((unsigned)rec[r]) >> 22;
                int p = atomicAdd(&sm.pe.lcur[key], 1);
                sm.pe.lrec[p] = rec[r];
            }
        }
        __syncthreads();
        int total = min(TE, N_INC - base);
        for (int i = t; i < total; i += 512) {
            int rr = sm.pe.lrec[i];
            int bk = ((unsigned)rr) >> 22;
            int dst = sm.pe.gbase[bk] + (i - sm.pe.lbase[bk]);
            if (dst < (bk + 1) * ECAP) staged_e[dst] = rr;
        }
    } else {
        int base = (pj - EPART) * TV;
        int rec[TV / 512];
        for (int i = t; i < NBV; i += 512) sm.pn.lhist[i] = 0;
        __syncthreads();
#pragma unroll
        for (int r = 0; r < TV / 512; ++r) {
            int idx = base + r * 512 + t;
            rec[r] = -1;
            if (idx < N_INC) {
                int e = ei[idx], v = ni[idx];
                int key = v >> 8;
                rec[r] = e | ((v & 255) << 15) | (key << 23);
                atomicAdd(&sm.pn.lhist[key], 1);
            }
        }
        __syncthreads();
        int h = (t < NBV) ? sm.pn.lhist[t] : 0;
        int ex = block_exscan512(h, sm.pn.sc);
        if (t < NBV) {
            sm.pn.lbase[t] = ex; sm.pn.lcur[t] = ex;
            sm.pn.gbase[t] = h ? (t * VCAP + atomicAdd(&cnt_bv[t * CPAD], h)) : 0;
        }
        __syncthreads();
#pragma unroll
        for (int r = 0; r < TV / 512; ++r) {
            if (rec[r] != -1) {
                int key = ((unsigned)rec[r]) >> 23;
                int p = atomicAdd(&sm.pn.lcur[key], 1);
                sm.pn.lrec[p] = rec[r];
            }
        }
        __syncthreads();
        int total = min(TV, N_INC - base);
        for (int i = t; i < total; i += 512) {
            int rr = sm.pn.lrec[i];
            int bk = ((unsigned)rr) >> 23;
            int dst = sm.pn.gbase[bk] + (i - sm.pn.lbase[bk]);
            if (dst < (bk + 1) * VCAP) staged_v[dst] = rr;
        }
    }
}

// ---------------- K2: edge sort + fused gatherA layer-1 (625) | node sort (392) -
union SMemS {
    struct { int lsort[ECAP]; int hist[EBS]; int cursor[EBS]; int lbeg[EBS]; } e;
    struct { int lsort[VCAP]; int hist[VBS]; int cursor[VBS]; int sc[8]; } v;
};

__global__ __launch_bounds__(512) void sortE_gA1_sortN_kernel(
    const int* __restrict__ cnt_be, int* __restrict__ staged_e,
    int2* __restrict__ off_e2,
    const int* __restrict__ cnt_bv, int* __restrict__ staged_v,
    int2* __restrict__ off_v2,
    const float* __restrict__ T, const float* __restrict__ w,
    float* __restrict__ e_den, float* __restrict__ e_feat) {
    __shared__ SMemS sm;
    int t = threadIdx.x;
    if (blockIdx.x < NBE) {
        int b = blockIdx.x;
        int beg = b * ECAP, cnt = min(cnt_be[b * CPAD], ECAP);
        if (t < EBS) sm.e.hist[t] = 0;
        __syncthreads();
        int rec[4], key[4], nr = 0;
#pragma unroll
        for (int r = 0; r < 4; ++r) {
            int k = r * 512 + t;
            if (k < cnt) {
                rec[nr] = staged_e[beg + k];
                key[nr] = (rec[nr] >> 17) & 31;
                atomicAdd(&sm.e.hist[key[nr]], 1);
                ++nr;
            }
        }
        __syncthreads();
        if (t < EBS) {
            int hh = sm.e.hist[t], s = hh;
#pragma unroll
            for (int o = 1; o < EBS; o <<= 1) {
                int x = __shfl_up(s, o, 64);
                if (t >= o) s += x;
            }
            int ex = s - hh;
            sm.e.cursor[t] = ex; sm.e.lbeg[t] = ex;
            off_e2[b * EBS + t] = make_int2(beg + ex, beg + ex + hh);
        }
        __syncthreads();
        for (int r = 0; r < nr; ++r) {
            int p = atomicAdd(&sm.e.cursor[key[r]], 1);
            sm.e.lsort[p] = rec[r];
        }
        __syncthreads();
        // writeback sorted records for gatherA layer-2
        for (int i = t; i < cnt; i += 512) staged_e[beg + i] = sm.e.lsort[i];
        // fused gatherA layer-1: 32 edges x 16 lanes, records from LDS
        int el = t >> 4, j = t & 15;
        int lo = sm.e.lbeg[el], hi = lo + sm.e.hist[el];
        float acc = 0.f;
        int k = lo;
        for (; k + 4 <= hi; k += 4) {           // 4-deep MLP
            int r0 = sm.e.lsort[k]     & 0x1FFFF;
            int r1 = sm.e.lsort[k + 1] & 0x1FFFF;
            int r2 = sm.e.lsort[k + 2] & 0x1FFFF;
            int r3 = sm.e.lsort[k + 3] & 0x1FFFF;
            float t0 = T[(size_t)r0 * D_H + j];
            float t1 = T[(size_t)r1 * D_H + j];
            float t2 = T[(size_t)r2 * D_H + j];
            float t3 = T[(size_t)r3 * D_H + j];
            acc += t0; acc += t1; acc += t2; acc += t3;
        }
        for (; k < hi; ++k) acc += T[(size_t)(sm.e.lsort[k] & 0x1FFFF) * D_H + j];
        // denominator: lanes split the w-gather, xor-reduce within 16-cluster
        float den = 0.f;
        for (int k2 = lo + j; k2 < hi; k2 += 16) den += w[sm.e.lsort[k2] & 0x1FFFF];
#pragma unroll
        for (int o = 1; o < 16; o <<= 1) den += __shfl_xor(den, o, 64);
        int e = b * EBS + el;                    // 625*32 == 20000 exactly
        e_feat[(size_t)e * D_H + j] = acc / fmaxf(den, 1e-6f);
        if (j == 0) e_den[e] = den;
    } else {
        int b = blockIdx.x - NBE;
        int beg = b * VCAP, cnt = min(cnt_bv[b * CPAD], VCAP);
        for (int i = t; i < VBS; i += 512) sm.v.hist[i] = 0;
        __syncthreads();
        int rec[5], key[5], nr = 0;
#pragma unroll
        for (int r = 0; r < 5; ++r) {
            int k = r * 512 + t;
            if (k < cnt) {
                rec[nr] = staged_v[beg + k];
                key[nr] = (rec[nr] >> 15) & 255;
                atomicAdd(&sm.v.hist[key[nr]], 1);
                ++nr;
            }
        }
        __syncthreads();
        int hh = (t < VBS) ? sm.v.hist[t] : 0;
        int ex = block_exscan512(hh, sm.v.sc);
        if (t < VBS) {
            sm.v.cursor[t] = ex;
            int n = b * VBS + t;
            if (n < N_NODES) off_v2[n] = make_int2(beg + ex, beg + ex + hh);
        }
        __syncthreads();
        for (int r = 0; r < nr; ++r) {
            int p = atomicAdd(&sm.v.cursor[key[r]], 1);
            sm.v.lsort[p] = rec[r];
        }
        __syncthreads();
        for (int i = t; i < cnt; i += 512) staged_v[beg + i] = sm.v.lsort[i];
    }
}

// ---------------- K3: gatherB layer 1: 4 lanes/node, relu(mean+b1)*w ------------
__global__ __launch_bounds__(512) void gatherB1_kernel(
    const int2* __restrict__ off_v2, const int* __restrict__ staged_v,
    const float* __restrict__ e_feat, const float* __restrict__ w,
    const float* __restrict__ b1, float* __restrict__ out) {
    int t = blockIdx.x * 512 + threadIdx.x;
    int n = t >> 2;
    if (n >= N_NODES) return;
    int c = (t & 3) << 2;
    int2 be = off_v2[n];
    f32x4 acc = {0.f, 0.f, 0.f, 0.f};
    for (int k = be.x; k < be.y; ++k) {
        int e = staged_v[k] & 0x7FFF;
        acc += *(const f32x4*)(e_feat + (size_t)e * D_H + c);
    }
    float inv = 1.f / fmaxf((float)(be.y - be.x), 1.f);
    f32x4 bb = *(const f32x4*)(b1 + c);
    float wn = w[n];
    f32x4 r;
#pragma unroll
    for (int i = 0; i < 4; ++i) r[i] = fmaxf(acc[i] * inv + bb[i], 0.f) * wn;
    *(f32x4*)(out + (size_t)n * D_H + c) = r;
}

// ---------------- K4: gatherA layer-2 (reuses e_den, sorted staged_e) -----------
__global__ __launch_bounds__(512) void gatherA2_kernel(
    const int2* __restrict__ off_e2, const int* __restrict__ staged_e,
    const float* __restrict__ X, const float* __restrict__ e_den,
    float* __restrict__ e_feat) {
    int e = (blockIdx.x * 512 + threadIdx.x) >> 6;
    if (e >= N_EDGES) return;
    int lane = threadIdx.x & 63;
    int g = lane >> 2, c = (lane & 3) << 2;
    int2 be = off_e2[e];
    f32x4 acc = {0.f, 0.f, 0.f, 0.f};
    for (int k = be.x + g; k < be.y; k += 16) {
        int rec = staged_e[k];
        int v = rec & 0x1FFFF;
        acc += *(const f32x4*)(X + (size_t)v * D_H + c);
    }
#pragma unroll
    for (int s = 4; s <= 32; s <<= 1) {
        acc[0] += __shfl_xor(acc[0], s, 64);
        acc[1] += __shfl_xor(acc[1], s, 64);
        acc[2] += __shfl_xor(acc[2], s, 64);
        acc[3] += __shfl_xor(acc[3], s, 64);
    }
    if (lane < 4) {
        float inv = 1.f / fmaxf(e_den[e], 1e-6f);
        f32x4 r = acc * inv;
        *(f32x4*)(e_feat + (size_t)e * D_H + c) = r;
    }
}

// ---------------- K5: gatherB layer 2 + W2 matmul + log_softmax -----------------
__global__ __launch_bounds__(512) void gatherB2_final_kernel(
    const int2* __restrict__ off_v2, const int* __restrict__ staged_v,
    const float* __restrict__ e_feat,
    const float* __restrict__ W2, const float* __restrict__ b2,
    float* __restrict__ out) {
    __shared__ float sy[128 * 20];
    __shared__ float sW2[D_H * D_OUT];
    __shared__ float sb2[D_OUT];
    int t = threadIdx.x;
    for (int i = t; i < D_H * D_OUT; i += 512) sW2[i] = W2[i];
    if (t < D_OUT) sb2[t] = b2[t];
    int nl = t >> 2, c = (t & 3) << 2;
    int n = blockIdx.x * 128 + nl;
    f32x4 y = {0.f, 0.f, 0.f, 0.f};
    if (n < N_NODES) {
        int2 be = off_v2[n];
        f32x4 acc = {0.f, 0.f, 0.f, 0.f};
        for (int k = be.x; k < be.y; ++k) {
            int e = staged_v[k] & 0x7FFF;
            acc += *(const f32x4*)(e_feat + (size_t)e * D_H + c);
        }
        float inv = 1.f / fmaxf((float)(be.y - be.x), 1.f);
        y = acc * inv;
    }
    *(f32x4*)(sy + nl * 20 + c) = y;
    __syncthreads();
    if (n >= N_NODES) return;
    int c0 = (t & 3) * 10;
    float z[10];
#pragma unroll
    for (int i = 0; i < 10; ++i) z[i] = sb2[c0 + i];
#pragma unroll
    for (int jj = 0; jj < D_H; ++jj) {
        float yy = sy[nl * 20 + jj];
#pragma unroll
        for (int i = 0; i < 10; ++i) z[i] += yy * sW2[jj * D_OUT + c0 + i];
    }
    float m = z[0];
#pragma unroll
    for (int i = 1; i < 10; ++i) m = fmaxf(m, z[i]);
    m = fmaxf(m, __shfl_xor(m, 1, 64));
    m = fmaxf(m, __shfl_xor(m, 2, 64));
    float se = 0.f;
#pragma unroll
    for (int i = 0; i < 10; ++i) se += __expf(z[i] - m);
    se += __shfl_xor(se, 1, 64);
    se += __shfl_xor(se, 2, 64);
    float lse = m + __logf(se);
    float* op = out + (size_t)n * D_OUT + c0;
#pragma unroll
    for (int i = 0; i < 10; ++i) op[i] = z[i] - lse;
}

extern "C" void kernel_launch(void* const* d_in, const int* in_sizes, int n_in,
                              void* d_out, int out_size, void* d_ws, size_t ws_size,
                              hipStream_t stream) {
    const float* H  = (const float*)d_in[0];
    const float* w  = (const float*)d_in[1];
    const int*   ni = (const int*)d_in[2];
    const int*   ei = (const int*)d_in[3];
    const float* W1 = (const float*)d_in[4];
    const float* b1 = (const float*)d_in[5];
    const float* W2 = (const float*)d_in[6];
    const float* b2 = (const float*)d_in[7];
    float* out = (float*)d_out;

    // workspace layout (4-byte words)
    int*            ws_i     = (int*)d_ws;
    int*            cnt_be   = ws_i + 0;                      // 625*16 = 10000
    int*            cnt_bv   = ws_i + 10000;                  // 392*16 = 6272
    unsigned short* bfrag    = (unsigned short*)(ws_i + 16272); // 4096 ush
    int2*           off_e2   = (int2*)(ws_i + 18320);         // 20000 int2
    int2*           off_v2   = (int2*)(ws_i + 58320);         // 100000 int2
    int*            staged_e = ws_i + 258320;                 // 625*1600
    int*            staged_v = ws_i + 1258320;                // 392*2400
    float*          e_den    = (float*)(ws_i + 2199120);      // 20000
    float*          T        = (float*)(ws_i + 2219120);      // 1,600,000
    float*          e_feat   = (float*)(ws_i + 3819120);      // 320,000
    float*          x1       = (float*)(ws_i + 4139120);      // 1,600,000
    // total 5,739,120 words = 23.0 MB

    init_kernel<<<1, 512, 0, stream>>>(W1, bfrag, cnt_be);

    part_gemm_kernel<<<GRID_K1, 512, 0, stream>>>(
        ni, ei, w, cnt_be, cnt_bv, staged_e, staged_v, H, bfrag, T);

    // edge sort + fused layer-1 edge aggregation || node sort
    sortE_gA1_sortN_kernel<<<NBE + NBV, 512, 0, stream>>>(
        cnt_be, staged_e, off_e2, cnt_bv, staged_v, off_v2, T, w, e_den, e_feat);

    gatherB1_kernel<<<782, 512, 0, stream>>>(off_v2, staged_v, e_feat, w, b1, x1);

    gatherA2_kernel<<<2500, 512, 0, stream>>>(off_e2, staged_e, x1, e_den, e_feat);

    gatherB2_final_kernel<<<782, 512, 0, stream>>>(
        off_v2, staged_v, e_feat, W2, b2, out);
}